// Round 1
// baseline (244.279 us; speedup 1.0000x reference)
//
#include <hip/hip_runtime.h>

#define N_NODES 10000
#define N_EDGES 320000
#define N_PAIRS 8192
#define IN_CH   128
#define HIDDEN  256
#define WPR     320   // u32 words per adjacency bitset row (320*32 = 10240 >= 10000)
#define TILE_B  32    // pairs per block in the MLP kernel

// ---------------------------------------------------------------- adjacency
__global__ __launch_bounds__(256) void build_adj_kernel(const int* __restrict__ ei,
                                                        unsigned int* __restrict__ adj) {
    int e = blockIdx.x * blockDim.x + threadIdx.x;
    if (e >= N_EDGES) return;
    int u = ei[e];
    int v = ei[N_EDGES + e];
    atomicOr(&adj[(size_t)u * WPR + (v >> 5)], 1u << (v & 31));
    atomicOr(&adj[(size_t)v * WPR + (u >> 5)], 1u << (u & 31));
}

// ------------------------------------------------- per-pair xs = [xij, cn_emb]
__global__ __launch_bounds__(256) void pair_xs_kernel(const float* __restrict__ x,
                                                      const int* __restrict__ tei,
                                                      const unsigned int* __restrict__ adj,
                                                      float* __restrict__ xs) {
    int p = blockIdx.x;
    int tid = threadIdx.x;
    int i = tei[p];
    int j = tei[N_PAIRS + p];

    __shared__ float cn_emb[IN_CH];
    if (tid < IN_CH) cn_emb[tid] = 0.0f;
    __syncthreads();

    const unsigned int* ri = adj + (size_t)i * WPR;
    const unsigned int* rj = adj + (size_t)j * WPR;
    for (int w = tid; w < WPR; w += 256) {
        unsigned int m = ri[w] & rj[w];
        while (m) {
            int b = __builtin_ctz(m);
            m &= m - 1;
            int n = w * 32 + b;
            const float* xn = x + (size_t)n * IN_CH;
            // expected ~0.4 common neighbors per pair -> this path is rare
            for (int d = 0; d < IN_CH; ++d) atomicAdd(&cn_emb[d], xn[d]);
        }
    }
    __syncthreads();

    if (tid < IN_CH) {
        float xij = x[(size_t)i * IN_CH + tid] * x[(size_t)j * IN_CH + tid];
        xs[(size_t)p * (2 * IN_CH) + tid] = xij;
        xs[(size_t)p * (2 * IN_CH) + IN_CH + tid] = cn_emb[tid];
    }
}

// ------------------------------------------------------------- W1 transpose
__global__ __launch_bounds__(256) void transpose_w1_kernel(const float* __restrict__ W1,
                                                           float* __restrict__ W1T) {
    int k = blockIdx.x;    // 256 blocks
    int h = threadIdx.x;   // 256 threads, coalesced store
    W1T[(size_t)k * HIDDEN + h] = W1[(size_t)h * HIDDEN + k];
}

// ---------------------------------------------------------------------- MLP
__global__ __launch_bounds__(256) void mlp_kernel(const float* __restrict__ xs,
                                                  const float* __restrict__ W1T,
                                                  const float* __restrict__ b1,
                                                  const float* __restrict__ W2,
                                                  const float* __restrict__ b2,
                                                  float* __restrict__ out) {
    __shared__ float s_xs[TILE_B * HIDDEN];   // 32 KB, reused as contrib buffer
    __shared__ float part[TILE_B][8];

    int b0 = blockIdx.x * TILE_B;
    int tid = threadIdx.x;

    // stage xs tile (coalesced)
    for (int t = tid; t < TILE_B * HIDDEN; t += 256) {
        s_xs[t] = xs[(size_t)b0 * HIDDEN + t];
    }
    __syncthreads();

    // thread h computes hidden unit h for all TILE_B pairs
    float acc[TILE_B];
#pragma unroll
    for (int b = 0; b < TILE_B; ++b) acc[b] = 0.0f;

    const int h = tid;
    for (int k = 0; k < HIDDEN; ++k) {
        float w = W1T[k * HIDDEN + h];          // coalesced, L2-hot
#pragma unroll
        for (int b = 0; b < TILE_B; ++b)
            acc[b] = fmaf(s_xs[b * HIDDEN + k], w, acc[b]);  // LDS broadcast
    }

    float bias = b1[h];
    float w2 = W2[h];
    __syncthreads();   // done reading s_xs as xs-tile

    // contrib[h][b] = W2[h] * relu(acc + b1[h])
#pragma unroll
    for (int b = 0; b < TILE_B; ++b) {
        float hv = fmaxf(acc[b] + bias, 0.0f);
        s_xs[h * TILE_B + b] = w2 * hv;
    }
    __syncthreads();

    // reduce over h: thread = (b, chunk c of 32 h's)
    int b = tid >> 3, c = tid & 7;
    float s = 0.0f;
#pragma unroll
    for (int t = 0; t < 32; ++t) s += s_xs[(c * 32 + t) * TILE_B + b];
    part[b][c] = s;
    __syncthreads();

    if (tid < TILE_B) {
        float r = b2[0];
#pragma unroll
        for (int cc = 0; cc < 8; ++cc) r += part[tid][cc];
        out[b0 + tid] = r;
    }
}

// -------------------------------------------------------------------- launch
extern "C" void kernel_launch(void* const* d_in, const int* in_sizes, int n_in,
                              void* d_out, int out_size, void* d_ws, size_t ws_size,
                              hipStream_t stream) {
    const float* x  = (const float*)d_in[0];
    const int*   ei = (const int*)d_in[1];
    const int*   tei = (const int*)d_in[2];
    const float* W1 = (const float*)d_in[3];
    const float* b1 = (const float*)d_in[4];
    const float* W2 = (const float*)d_in[5];
    const float* b2 = (const float*)d_in[6];
    float* out = (float*)d_out;

    unsigned char* ws = (unsigned char*)d_ws;
    const size_t adj_bytes = (size_t)N_NODES * WPR * sizeof(unsigned int);   // 12.8 MB
    const size_t xs_bytes  = (size_t)N_PAIRS * (2 * IN_CH) * sizeof(float);  // 8 MB
    unsigned int* adj = (unsigned int*)ws;
    float* xs  = (float*)(ws + adj_bytes);
    float* W1T = (float*)(ws + adj_bytes + xs_bytes);                        // 256 KB

    hipMemsetAsync(adj, 0, adj_bytes, stream);
    build_adj_kernel<<<(N_EDGES + 255) / 256, 256, 0, stream>>>(ei, adj);
    pair_xs_kernel<<<N_PAIRS, 256, 0, stream>>>(x, tei, adj, xs);
    transpose_w1_kernel<<<HIDDEN, HIDDEN, 0, stream>>>(W1, W1T);
    mlp_kernel<<<N_PAIRS / TILE_B, 256, 0, stream>>>(xs, W1T, b1, W2, b2, out);
}

// Round 2
// 150.824 us; speedup vs baseline: 1.6196x; 1.6196x over previous
//
#include <hip/hip_runtime.h>

#define N_NODES 10000
#define N_EDGES 320000
#define N_PAIRS 8192
#define IN_CH   128
#define HIDDEN  256
#define WPR     320   // u32 words per adjacency bitset row (320*32 = 10240 >= 10000)
#define WPR4    (WPR / 4)
#define TILE_B  32    // pairs per block in the fused kernel
#define CN_CAP  16    // common-neighbor list capacity per pair (overflow -> atomic path)

// ---------------------------------------------------------------- adjacency
__global__ __launch_bounds__(256) void build_adj_kernel(const int* __restrict__ ei,
                                                        unsigned int* __restrict__ adj) {
    int e = blockIdx.x * blockDim.x + threadIdx.x;
    if (e >= N_EDGES) return;
    int u = ei[e];
    int v = ei[N_EDGES + e];
    atomicOr(&adj[(size_t)u * WPR + (v >> 5)], 1u << (v & 31));
    atomicOr(&adj[(size_t)v * WPR + (u >> 5)], 1u << (u & 31));
}

// ------------------------------------------------------------- W1 pack
// W1 is [HIDDEN][2*IN_CH] row-major. Pack so thread h can load float4 of 4
// consecutive k at W1P[k4*HIDDEN + h]  (coalesced across h).
__global__ __launch_bounds__(256) void pack_w1_kernel(const float* __restrict__ W1,
                                                      float4* __restrict__ W1P) {
    int k4 = blockIdx.x;    // 64 blocks
    int h  = threadIdx.x;   // 256 threads
    const float* src = W1 + (size_t)h * HIDDEN + k4 * 4;
    W1P[(size_t)k4 * HIDDEN + h] = make_float4(src[0], src[1], src[2], src[3]);
}

// ------------------------------------------------- fused pair-xs + MLP
__global__ __launch_bounds__(256) void fused_kernel(const float* __restrict__ x,
                                                    const int* __restrict__ tei,
                                                    const unsigned int* __restrict__ adj,
                                                    const float4* __restrict__ W1P,
                                                    const float* __restrict__ b1,
                                                    const float* __restrict__ W2,
                                                    const float* __restrict__ b2,
                                                    float* __restrict__ out) {
    __shared__ float s_xs[TILE_B][2 * IN_CH];   // 32 KB; reused as contrib buffer
    __shared__ int   s_ij[TILE_B][2];
    __shared__ int   s_cnt[TILE_B];
    __shared__ int   s_cnl[TILE_B][CN_CAP];

    const int tid = threadIdx.x;
    const int p0 = blockIdx.x * TILE_B;

    if (tid < TILE_B) {
        s_ij[tid][0] = tei[p0 + tid];
        s_ij[tid][1] = tei[N_PAIRS + p0 + tid];
        s_cnt[tid] = 0;
    }
    // zero the cn_emb half of xs
    for (int t = tid; t < TILE_B * IN_CH; t += 256)
        s_xs[t >> 7][IN_CH + (t & 127)] = 0.0f;
    __syncthreads();

    // ---- phase 1a: bitset intersection, collect CN node ids
    const int b = tid >> 3;          // pair within tile (8 threads per pair)
    const int s = tid & 7;
    const int i = s_ij[b][0];
    const int j = s_ij[b][1];
    const uint4* ri4 = (const uint4*)(adj + (size_t)i * WPR);
    const uint4* rj4 = (const uint4*)(adj + (size_t)j * WPR);
    for (int q = s; q < WPR4; q += 8) {
        uint4 a = ri4[q];
        uint4 c = rj4[q];
        unsigned int m[4] = { a.x & c.x, a.y & c.y, a.z & c.z, a.w & c.w };
#pragma unroll
        for (int w = 0; w < 4; ++w) {
            unsigned int mm = m[w];
            while (mm) {
                int bit = __builtin_ctz(mm);
                mm &= mm - 1;
                int n = q * 128 + w * 32 + bit;
                int pos = atomicAdd(&s_cnt[b], 1);
                if (pos < CN_CAP) {
                    s_cnl[b][pos] = n;
                } else {   // overflow (astronomically rare): direct LDS atomics
                    const float* xn = x + (size_t)n * IN_CH;
                    for (int d = 0; d < IN_CH; ++d)
                        atomicAdd(&s_xs[b][IN_CH + d], xn[d]);
                }
            }
        }
    }

    // ---- phase 1b: xij (each of the 8 threads owns 16 channels = 4 float4)
    {
        const float4* xi4 = (const float4*)(x + (size_t)i * IN_CH);
        const float4* xj4 = (const float4*)(x + (size_t)j * IN_CH);
        float4* xd = (float4*)&s_xs[b][0];
#pragma unroll
        for (int f = 0; f < 4; ++f) {
            float4 va = xi4[s * 4 + f];
            float4 vb = xj4[s * 4 + f];
            xd[s * 4 + f] = make_float4(va.x * vb.x, va.y * vb.y, va.z * vb.z, va.w * vb.w);
        }
    }
    __syncthreads();

    // ---- phase 1c: accumulate common-neighbor features (owner-computes)
    {
        int cnt = s_cnt[b];
        if (cnt > CN_CAP) cnt = CN_CAP;
        float4* dst = (float4*)&s_xs[b][IN_CH];
        for (int c = 0; c < cnt; ++c) {
            const float4* xn4 = (const float4*)(x + (size_t)s_cnl[b][c] * IN_CH);
#pragma unroll
            for (int f = 0; f < 4; ++f) {
                float4 v = xn4[s * 4 + f];
                float4 d0 = dst[s * 4 + f];
                dst[s * 4 + f] = make_float4(d0.x + v.x, d0.y + v.y, d0.z + v.z, d0.w + v.w);
            }
        }
    }
    __syncthreads();

    // ---- phase 2: MLP. thread h owns hidden unit h for all TILE_B pairs.
    const int h = tid;
    float acc[TILE_B];
#pragma unroll
    for (int bb = 0; bb < TILE_B; ++bb) acc[bb] = 0.0f;

    const float4* xs4 = (const float4*)s_xs;   // [b][64] float4
    for (int k4 = 0; k4 < HIDDEN / 4; ++k4) {
        float4 w = W1P[k4 * HIDDEN + h];       // coalesced, L2-hot
#pragma unroll
        for (int bb = 0; bb < TILE_B; ++bb) {
            float4 xv = xs4[bb * 64 + k4];     // LDS broadcast
            acc[bb] = fmaf(xv.x, w.x, acc[bb]);
            acc[bb] = fmaf(xv.y, w.y, acc[bb]);
            acc[bb] = fmaf(xv.z, w.z, acc[bb]);
            acc[bb] = fmaf(xv.w, w.w, acc[bb]);
        }
    }

    const float bias = b1[h];
    const float w2 = W2[h];
    __syncthreads();   // done reading s_xs as xs tile

    // contrib[b][h] layout: conflict-free writes (lanes -> consecutive banks)
    float* s_c = &s_xs[0][0];
#pragma unroll
    for (int bb = 0; bb < TILE_B; ++bb)
        s_c[bb * HIDDEN + h] = w2 * fmaxf(acc[bb] + bias, 0.0f);
    __syncthreads();

    // reduce over h: wave w handles pairs [w*8, w*8+8)
    const int wave = tid >> 6;
    const int lane = tid & 63;
    const float bout = b2[0];
    for (int bb = wave * 8; bb < wave * 8 + 8; ++bb) {
        float v = s_c[bb * HIDDEN + lane]
                + s_c[bb * HIDDEN + lane + 64]
                + s_c[bb * HIDDEN + lane + 128]
                + s_c[bb * HIDDEN + lane + 192];
#pragma unroll
        for (int off = 32; off > 0; off >>= 1)
            v += __shfl_down(v, off);
        if (lane == 0) out[p0 + bb] = v + bout;
    }
}

// -------------------------------------------------------------------- launch
extern "C" void kernel_launch(void* const* d_in, const int* in_sizes, int n_in,
                              void* d_out, int out_size, void* d_ws, size_t ws_size,
                              hipStream_t stream) {
    const float* x   = (const float*)d_in[0];
    const int*   ei  = (const int*)d_in[1];
    const int*   tei = (const int*)d_in[2];
    const float* W1  = (const float*)d_in[3];
    const float* b1  = (const float*)d_in[4];
    const float* W2  = (const float*)d_in[5];
    const float* b2  = (const float*)d_in[6];
    float* out = (float*)d_out;

    unsigned char* ws = (unsigned char*)d_ws;
    const size_t adj_bytes = (size_t)N_NODES * WPR * sizeof(unsigned int);   // 12.8 MB
    unsigned int* adj = (unsigned int*)ws;
    float4* W1P = (float4*)(ws + adj_bytes);                                 // 256 KB

    hipMemsetAsync(adj, 0, adj_bytes, stream);
    build_adj_kernel<<<(N_EDGES + 255) / 256, 256, 0, stream>>>(ei, adj);
    pack_w1_kernel<<<HIDDEN / 4, 256, 0, stream>>>(W1, W1P);
    fused_kernel<<<N_PAIRS / TILE_B, 256, 0, stream>>>(x, tei, adj, W1P, b1, W2, b2, out);
}

// Round 3
// 91.255 us; speedup vs baseline: 2.6769x; 1.6528x over previous
//
#include <hip/hip_runtime.h>

#define N_NODES 10000
#define N_EDGES 320000
#define N_PAIRS 8192
#define IN_CH   128
#define HIDDEN  256
#define WPR     320   // u32 words per adjacency bitset row (320*32 = 10240 >= 10000)
#define WPR4    (WPR / 4)
#define TILE_B  8     // pairs per block (1024 blocks -> 4 blocks/CU -> 16 waves/CU)
#define TPP     (256 / TILE_B)   // threads per pair = 32
#define CN_CAP  16    // common-neighbor list capacity per pair (overflow -> atomic path)

// ---------------------------------------------------------------- adjacency
__global__ __launch_bounds__(256) void build_adj_kernel(const int* __restrict__ ei,
                                                        unsigned int* __restrict__ adj) {
    int e = blockIdx.x * blockDim.x + threadIdx.x;
    if (e >= N_EDGES) return;
    int u = ei[e];
    int v = ei[N_EDGES + e];
    atomicOr(&adj[(size_t)u * WPR + (v >> 5)], 1u << (v & 31));
    atomicOr(&adj[(size_t)v * WPR + (u >> 5)], 1u << (u & 31));
}

// ------------------------------------------------------------- W1 pack
// W1 is [HIDDEN][2*IN_CH] row-major. Pack so thread h loads float4 of 4
// consecutive k at W1P[k4*HIDDEN + h]  (coalesced across h).
__global__ __launch_bounds__(256) void pack_w1_kernel(const float* __restrict__ W1,
                                                      float4* __restrict__ W1P) {
    int k4 = blockIdx.x;    // 64 blocks
    int h  = threadIdx.x;   // 256 threads
    const float* src = W1 + (size_t)h * HIDDEN + k4 * 4;
    W1P[(size_t)k4 * HIDDEN + h] = make_float4(src[0], src[1], src[2], src[3]);
}

// ------------------------------------------------- fused pair-xs + MLP
__global__ __launch_bounds__(256) void fused_kernel(const float* __restrict__ x,
                                                    const int* __restrict__ tei,
                                                    const unsigned int* __restrict__ adj,
                                                    const float4* __restrict__ W1P,
                                                    const float* __restrict__ b1,
                                                    const float* __restrict__ W2,
                                                    const float* __restrict__ b2,
                                                    float* __restrict__ out) {
    __shared__ float s_xs[TILE_B][2 * IN_CH];   // 8 KB; reused as contrib buffer
    __shared__ int   s_ij[TILE_B][2];
    __shared__ int   s_cnt[TILE_B];
    __shared__ int   s_cnl[TILE_B][CN_CAP];

    const int tid = threadIdx.x;
    const int p0 = blockIdx.x * TILE_B;

    if (tid < TILE_B) {
        s_ij[tid][0] = tei[p0 + tid];
        s_ij[tid][1] = tei[N_PAIRS + p0 + tid];
        s_cnt[tid] = 0;
    }
    // zero the cn_emb half of xs
    for (int t = tid; t < TILE_B * IN_CH; t += 256)
        s_xs[t >> 7][IN_CH + (t & 127)] = 0.0f;
    __syncthreads();

    // ---- phase 1a: bitset intersection, collect CN node ids
    const int b = tid / TPP;          // pair within tile (32 threads per pair)
    const int s = tid % TPP;
    const int i = s_ij[b][0];
    const int j = s_ij[b][1];
    const uint4* ri4 = (const uint4*)(adj + (size_t)i * WPR);
    const uint4* rj4 = (const uint4*)(adj + (size_t)j * WPR);
    for (int q = s; q < WPR4; q += TPP) {
        uint4 a = ri4[q];
        uint4 c = rj4[q];
        unsigned int m[4] = { a.x & c.x, a.y & c.y, a.z & c.z, a.w & c.w };
#pragma unroll
        for (int w = 0; w < 4; ++w) {
            unsigned int mm = m[w];
            while (mm) {
                int bit = __builtin_ctz(mm);
                mm &= mm - 1;
                int n = q * 128 + w * 32 + bit;
                int pos = atomicAdd(&s_cnt[b], 1);
                if (pos < CN_CAP) {
                    s_cnl[b][pos] = n;
                } else {   // overflow (astronomically rare): direct LDS atomics
                    const float* xn = x + (size_t)n * IN_CH;
                    for (int d = 0; d < IN_CH; ++d)
                        atomicAdd(&s_xs[b][IN_CH + d], xn[d]);
                }
            }
        }
    }

    // ---- phase 1b: xij (each of the 32 threads owns 4 channels = 1 float4)
    {
        const float4* xi4 = (const float4*)(x + (size_t)i * IN_CH);
        const float4* xj4 = (const float4*)(x + (size_t)j * IN_CH);
        float4* xd = (float4*)&s_xs[b][0];
        float4 va = xi4[s];
        float4 vb = xj4[s];
        xd[s] = make_float4(va.x * vb.x, va.y * vb.y, va.z * vb.z, va.w * vb.w);
    }
    __syncthreads();

    // ---- phase 1c: accumulate common-neighbor features (owner-computes)
    {
        int cnt = s_cnt[b];
        if (cnt > CN_CAP) cnt = CN_CAP;
        float4* dst = (float4*)&s_xs[b][IN_CH];
        float4 d0 = dst[s];
        for (int c = 0; c < cnt; ++c) {
            const float4* xn4 = (const float4*)(x + (size_t)s_cnl[b][c] * IN_CH);
            float4 v = xn4[s];
            d0 = make_float4(d0.x + v.x, d0.y + v.y, d0.z + v.z, d0.w + v.w);
        }
        dst[s] = d0;
    }
    __syncthreads();

    // ---- phase 2: MLP. thread h owns hidden unit h for all TILE_B pairs.
    const int h = tid;
    float acc[TILE_B];
#pragma unroll
    for (int bb = 0; bb < TILE_B; ++bb) acc[bb] = 0.0f;

    const float4* xs4 = (const float4*)s_xs;   // [b][64] float4
    for (int k4 = 0; k4 < HIDDEN / 4; ++k4) {
        float4 w = W1P[k4 * HIDDEN + h];       // coalesced, L2-hot
#pragma unroll
        for (int bb = 0; bb < TILE_B; ++bb) {
            float4 xv = xs4[bb * 64 + k4];     // LDS broadcast
            acc[bb] = fmaf(xv.x, w.x, acc[bb]);
            acc[bb] = fmaf(xv.y, w.y, acc[bb]);
            acc[bb] = fmaf(xv.z, w.z, acc[bb]);
            acc[bb] = fmaf(xv.w, w.w, acc[bb]);
        }
    }

    const float bias = b1[h];
    const float w2 = W2[h];
    __syncthreads();   // done reading s_xs as xs tile

    // contrib[b][h] layout: conflict-free writes (lanes -> consecutive banks)
    float* s_c = &s_xs[0][0];
#pragma unroll
    for (int bb = 0; bb < TILE_B; ++bb)
        s_c[bb * HIDDEN + h] = w2 * fmaxf(acc[bb] + bias, 0.0f);
    __syncthreads();

    // reduce over h: wave w handles pairs [w*2, w*2+2)
    const int wave = tid >> 6;
    const int lane = tid & 63;
    const float bout = b2[0];
    for (int bb = wave * 2; bb < wave * 2 + 2; ++bb) {
        float v = s_c[bb * HIDDEN + lane]
                + s_c[bb * HIDDEN + lane + 64]
                + s_c[bb * HIDDEN + lane + 128]
                + s_c[bb * HIDDEN + lane + 192];
#pragma unroll
        for (int off = 32; off > 0; off >>= 1)
            v += __shfl_down(v, off);
        if (lane == 0) out[p0 + bb] = v + bout;
    }
}

// -------------------------------------------------------------------- launch
extern "C" void kernel_launch(void* const* d_in, const int* in_sizes, int n_in,
                              void* d_out, int out_size, void* d_ws, size_t ws_size,
                              hipStream_t stream) {
    const float* x   = (const float*)d_in[0];
    const int*   ei  = (const int*)d_in[1];
    const int*   tei = (const int*)d_in[2];
    const float* W1  = (const float*)d_in[3];
    const float* b1  = (const float*)d_in[4];
    const float* W2  = (const float*)d_in[5];
    const float* b2  = (const float*)d_in[6];
    float* out = (float*)d_out;

    unsigned char* ws = (unsigned char*)d_ws;
    const size_t adj_bytes = (size_t)N_NODES * WPR * sizeof(unsigned int);   // 12.8 MB
    unsigned int* adj = (unsigned int*)ws;
    float4* W1P = (float4*)(ws + adj_bytes);                                 // 256 KB

    hipMemsetAsync(adj, 0, adj_bytes, stream);
    build_adj_kernel<<<(N_EDGES + 255) / 256, 256, 0, stream>>>(ei, adj);
    pack_w1_kernel<<<HIDDEN / 4, 256, 0, stream>>>(W1, W1P);
    fused_kernel<<<N_PAIRS / TILE_B, 256, 0, stream>>>(x, tei, adj, W1P, b1, W2, b2, out);
}